// Round 3
// baseline (233.742 us; speedup 1.0000x reference)
//
#include <hip/hip_runtime.h>
#include <stdint.h>

#define D_ 256
#define NQ_ 512
#define NK_ 512
#define NP_ (NQ_*NK_)

typedef __attribute__((ext_vector_type(8))) __bf16 bf16x8;
typedef __attribute__((ext_vector_type(4))) float f32x4;

__device__ __forceinline__ unsigned short f2bf(float f) {
  unsigned u = __builtin_bit_cast(unsigned, f);
  u += 0x7FFFu + ((u >> 16) & 1u);   // RNE
  return (unsigned short)(u >> 16);
}
__device__ __forceinline__ unsigned encf(float f) {  // order-preserving float->uint
  unsigned u = __builtin_bit_cast(unsigned, f);
  return (u & 0x80000000u) ? ~u : (u | 0x80000000u);
}
__device__ __forceinline__ float decf(unsigned e) {
  unsigned u = (e & 0x80000000u) ? (e ^ 0x80000000u) : ~e;
  return __builtin_bit_cast(float, u);
}

// ---------------- K0: mask dtype sniff + min-slot init ----------------
__global__ void kinit(const unsigned* __restrict__ maskw,
                      unsigned* __restrict__ wsMin, unsigned* __restrict__ wsFlag) {
  int l = threadIdx.x;  // 64
  unsigned a01 = 1, af = 1;
  for (int i = 0; i < 4; ++i) {
    unsigned v = maskw[l*4 + i];
    a01 &= (v == 0u || v == 1u) ? 1u : 0u;
    af  &= (v == 0u || v == 0x3f800000u) ? 1u : 0u;
  }
  unsigned long long b01 = __ballot(a01 != 0), bf = __ballot(af != 0);
  if (l == 0) {
    *wsFlag = (b01 == ~0ull) ? 1u : ((bf == ~0ull) ? 2u : 0u); // 1=int32, 2=f32, 0=byte
    *wsMin = 0xFFFFFFFFu;
  }
}

// ---------------- Kc: elementwise bf16 conversions (no transposes) ----------------
// regions (blocks): [0,64) Cb=aW1[:,512:768]; [64,192) source_bf16; [192,448) mW1b;
// [448,576) mW2b; [576,640) aW1A; [640,704) aW1B
__global__ __launch_bounds__(256) void kconvert(
    const float* __restrict__ aW1, const float* __restrict__ source,
    const float* __restrict__ mW1, const float* __restrict__ mW2,
    unsigned short* __restrict__ Cb, unsigned short* __restrict__ srcbf,
    unsigned short* __restrict__ mW1b, unsigned short* __restrict__ mW2b,
    unsigned short* __restrict__ aW1A, unsigned short* __restrict__ aW1B) {
  const int b = blockIdx.x, t = threadIdx.x;
  const float* src; unsigned short* dst;
  if (b < 64)        { int j = b*1024 + t*4;       int e=j>>8, c=j&255; src = aW1 + e*768 + 512 + c; dst = Cb + j; }
  else if (b < 192)  { int j = (b-64)*1024 + t*4;  src = source + j;    dst = srcbf + j; }
  else if (b < 448)  { int j = (b-192)*1024 + t*4; src = mW1 + j;       dst = mW1b + j; }
  else if (b < 576)  { int j = (b-448)*1024 + t*4; src = mW2 + j;       dst = mW2b + j; }
  else if (b < 640)  { int j = (b-576)*1024 + t*4; int e=j>>8, c=j&255; src = aW1 + e*768 + c;       dst = aW1A + j; }
  else               { int j = (b-640)*1024 + t*4; int e=j>>8, c=j&255; src = aW1 + e*768 + 256 + c; dst = aW1B + j; }
  const float4 v = *(const float4*)src;
  ushort4 o; o.x=f2bf(v.x); o.y=f2bf(v.y); o.z=f2bf(v.z); o.w=f2bf(v.w);
  *(ushort4*)dst = o;
}

// ---------------- Kt: tiled transpose f32 [256][512] -> bf16 [512][ldd] ----------------
// block = 64x64 tile; grid 32 (4 d-tiles x 8 q-tiles)
__global__ __launch_bounds__(256) void ktransp(const float* __restrict__ src,
                                               unsigned short* __restrict__ dst, int ldd) {
  __shared__ float tile[64][65];
  const int bd = blockIdx.x >> 3;   // d-tile 0..3
  const int bq = blockIdx.x & 7;    // q-tile 0..7
  const int t = threadIdx.x;
  const int r = t >> 4, c4 = (t & 15) * 4;
  #pragma unroll
  for (int rr = 0; rr < 4; ++rr) {
    int dl = rr*16 + r;
    float4 v = *(const float4*)(src + (size_t)(bd*64 + dl)*512 + bq*64 + c4);
    tile[dl][c4+0] = v.x; tile[dl][c4+1] = v.y; tile[dl][c4+2] = v.z; tile[dl][c4+3] = v.w;
  }
  __syncthreads();
  #pragma unroll
  for (int rr = 0; rr < 4; ++rr) {
    int j = rr*16 + r;   // local q
    ushort4 o;
    o.x = f2bf(tile[c4+0][j]); o.y = f2bf(tile[c4+1][j]);
    o.z = f2bf(tile[c4+2][j]); o.w = f2bf(tile[c4+3][j]);
    *(ushort4*)(dst + (size_t)(bq*64 + j)*ldd + bd*64 + c4) = o;
  }
}

// ---------------- direct-from-global MFMA GEMM ----------------
// D[m][n] = sum_k A[m][k]*B[n][k] (+bias) ; A [M][lda], B [N][ldb] bf16 row-major-in-k
// EPI bits: 1=bf16-out, 2=relu, 4=bias[col], 8=bias[row]
template<int EPI, int KTILES>
__global__ __launch_bounds__(256) void gemm_k(
    const unsigned short* __restrict__ A, int lda,
    const unsigned short* __restrict__ B, int ldb,
    const float* __restrict__ bias,
    void* __restrict__ Dst, int ldd, int nTilesN) {
  const int t = threadIdx.x, w = t >> 6, l = t & 63, l15 = l & 15, g = l >> 4;
  const int bm = blockIdx.x / nTilesN, bn = blockIdx.x % nTilesN;
  const int m0 = bm*64 + w*16, n0 = bn*64;
  const unsigned short* Ap = A + (size_t)(m0 + l15)*lda + g*8;
  const unsigned short* Bp = B + (size_t)(n0 + l15)*ldb + g*8;
  f32x4 acc[4];
  #pragma unroll
  for (int n = 0; n < 4; ++n) acc[n] = (f32x4){0.f,0.f,0.f,0.f};
  #pragma unroll 2
  for (int kk = 0; kk < KTILES; ++kk) {
    bf16x8 a = *(const bf16x8*)(Ap + kk*32);
    #pragma unroll
    for (int n = 0; n < 4; ++n) {
      bf16x8 b = *(const bf16x8*)(Bp + (size_t)n*16*ldb + kk*32);
      acc[n] = __builtin_amdgcn_mfma_f32_16x16x32_bf16(a, b, acc[n], 0, 0, 0);
    }
  }
  #pragma unroll
  for (int n = 0; n < 4; ++n) {
    const int col = n0 + n*16 + l15;
    const float bc = (EPI & 4) ? bias[col] : 0.f;
    #pragma unroll
    for (int r = 0; r < 4; ++r) {
      const int m = m0 + g*4 + r;
      float v = acc[n][r] + bc;
      if (EPI & 8) v += bias[m];
      if (EPI & 2) v = fmaxf(v, 0.f);
      if (EPI & 1) ((unsigned short*)Dst)[(size_t)m*ldd + col] = f2bf(v);
      else         ((float*)Dst)[(size_t)m*ldd + col] = v;
    }
  }
}

// ---------------- KB: barrier-free fused scores GEMM ----------------
// block = 64 pairs, M=256 (4 waves x 64 e-rows), K=256. B-frags built directly
// from global scalar loads + cvt_pk; A-frags direct from L2-resident Cb.
__global__ __launch_bounds__(256) void kscores(
    const float* __restrict__ dist, const unsigned short* __restrict__ Cb,
    const float* __restrict__ Up, const float* __restrict__ Vm,
    const float* __restrict__ aW2, const float* __restrict__ ab2,
    float* __restrict__ outScores, unsigned* __restrict__ wsMin) {
  __shared__ float u_s[256], aw2_s[256];
  __shared__ float red[4][64];

  const int t = threadIdx.x;
  const int w = t >> 6;
  const int l = t & 63;
  const int l15 = l & 15;
  const int g = l >> 4;

  const int p0 = blockIdx.x * 64;
  const int q  = p0 >> 9;
  const int k0 = p0 & 511;

  u_s[t]   = Up[q*256 + t];
  aw2_s[t] = aW2[t];

  f32x4 acc[4][4];
  #pragma unroll
  for (int m = 0; m < 4; ++m)
    #pragma unroll
    for (int n = 0; n < 4; ++n) acc[m][n] = (f32x4){0.f, 0.f, 0.f, 0.f};

  // lane-fixed bases
  const float* drow = dist + (size_t)(g*8)*NP_ + (size_t)(p0 + l15);
  const unsigned short* Abase = Cb + (size_t)(w*64 + l15)*256 + g*8;

  #pragma unroll 2
  for (int kk = 0; kk < 8; ++kk) {
    bf16x8 a[4];
    #pragma unroll
    for (int m = 0; m < 4; ++m)
      a[m] = *(const bf16x8*)(Abase + (size_t)m*16*256 + kk*32);
    #pragma unroll
    for (int n = 0; n < 4; ++n) {
      float v[8];
      #pragma unroll
      for (int i = 0; i < 8; ++i)
        v[i] = drow[(size_t)(kk*32 + i)*NP_ + n*16];
      bf16x8 b;
      #pragma unroll
      for (int i = 0; i < 8; ++i) b[i] = (__bf16)v[i];   // -> v_cvt_pk_bf16_f32
      #pragma unroll
      for (int m = 0; m < 4; ++m)
        acc[m][n] = __builtin_amdgcn_mfma_f32_16x16x32_bf16(a[m], b, acc[m][n], 0, 0, 0);
    }
  }
  __syncthreads();   // u_s/aw2_s visibility for epilogue

  // epilogue: score[j] = ab2 + sum_e aW2[e]*relu(T + U' + V)
  float part[4];
  #pragma unroll
  for (int n = 0; n < 4; ++n) {
    int j = k0 + n*16 + l15;
    float s = 0.f;
    #pragma unroll
    for (int m = 0; m < 4; ++m) {
      #pragma unroll
      for (int r = 0; r < 4; ++r) {
        int e = w*64 + m*16 + g*4 + r;
        float gv = acc[m][n][r] + u_s[e] + Vm[e*512 + j];
        s += aw2_s[e] * fmaxf(gv, 0.f);
      }
    }
    s += __shfl_xor(s, 16);
    s += __shfl_xor(s, 32);
    part[n] = s;
  }
  if (l < 16) {
    #pragma unroll
    for (int n = 0; n < 4; ++n) red[w][n*16 + l] = part[n];
  }
  __syncthreads();
  if (t < 64) {
    float s = red[0][t] + red[1][t] + red[2][t] + red[3][t] + ab2[0];
    outScores[p0 + t] = s;
    float mn = s;
    #pragma unroll
    for (int off = 32; off; off >>= 1) mn = fminf(mn, __shfl_xor(mn, off));
    if (t == 0) atomicMin(wsMin, encf(mn));
  }
}

// ---------------- KS: mask + softmax -> masked scores (out) + prob bf16 ----------------
__global__ __launch_bounds__(256) void ksoftmax(
    const void* __restrict__ maskp,
    const unsigned* __restrict__ wsMin, const unsigned* __restrict__ wsFlag,
    float* __restrict__ scores, unsigned short* __restrict__ prob) {
  __shared__ float srow[512];
  __shared__ float redl[8];
  const int t = threadIdx.x, w = t >> 6, l = t & 63;
  const int q = blockIdx.x;
  const float neg = decf(*wsMin) - 20.0f;
  const unsigned flag = *wsFlag;

  for (int k = t; k < 512; k += 256) {
    float raw = scores[q*512 + k];
    bool mv;
    if (flag == 1)      mv = ((const int*)maskp)[q*512 + k] != 0;
    else if (flag == 2) mv = ((const float*)maskp)[q*512 + k] != 0.f;
    else                mv = ((const unsigned char*)maskp)[q*512 + k] != 0;
    float ms = raw + (mv ? 0.f : neg);
    scores[q*512 + k] = ms;
    srow[k] = ms;
  }
  __syncthreads();
  float lm = fmaxf(srow[t], srow[t + 256]);
  #pragma unroll
  for (int off = 32; off; off >>= 1) lm = fmaxf(lm, __shfl_xor(lm, off));
  if (l == 0) redl[w] = lm;
  __syncthreads();
  float rmax = fmaxf(fmaxf(redl[0], redl[1]), fmaxf(redl[2], redl[3]));
  float e0 = __expf(srow[t] - rmax), e1 = __expf(srow[t + 256] - rmax);
  float ls = e0 + e1;
  #pragma unroll
  for (int off = 32; off; off >>= 1) ls += __shfl_xor(ls, off);
  if (l == 0) redl[4 + w] = ls;
  __syncthreads();
  float inv = 1.0f / (redl[4] + redl[5] + redl[6] + redl[7]);
  prob[q*512 + t]       = f2bf(e0 * inv);
  prob[q*512 + t + 256] = f2bf(e1 * inv);
}

extern "C" void kernel_launch(void* const* d_in, const int* in_sizes, int n_in,
                              void* d_out, int out_size, void* d_ws, size_t ws_size,
                              hipStream_t stream) {
  const float* x      = (const float*)d_in[0];
  const float* source = (const float*)d_in[1];
  const float* dist   = (const float*)d_in[2];
  const void*  mask   = (const void*)d_in[3];
  const float* aW1    = (const float*)d_in[4];
  const float* ab1    = (const float*)d_in[5];
  const float* aW2    = (const float*)d_in[6];
  const float* ab2    = (const float*)d_in[7];
  const float* mW1    = (const float*)d_in[8];
  const float* mb1    = (const float*)d_in[9];
  const float* mW2    = (const float*)d_in[10];
  const float* mb2    = (const float*)d_in[11];

  float* outMain = (float*)d_out;             // (1,256,512)
  float* scores  = outMain + 256*512;         // (1,512,512)

  char* ws = (char*)d_ws;
  unsigned* wsMin  = (unsigned*)ws;
  unsigned* wsFlag = wsMin + 1;
  unsigned short* Cb    = (unsigned short*)(ws + 1024);     // 256x256 bf16
  float*          Up    = (float*)(ws + 132096);            // 512x256 f32
  float*          Vm    = (float*)(ws + 656384);            // 256x512 f32
  unsigned short* srcbf = (unsigned short*)(ws + 1180672);  // 256x512 bf16 [d][k]
  unsigned short* srcT  = (unsigned short*)(ws + 1442816);  // 512x256 bf16 [k][c]
  unsigned short* mW1b  = (unsigned short*)(ws + 1704960);  // 512x512 bf16
  unsigned short* mW2b  = (unsigned short*)(ws + 2229248);  // 256x512 bf16
  unsigned short* aW1A  = (unsigned short*)(ws + 2491392);  // 256x256 bf16
  unsigned short* aW1B  = (unsigned short*)(ws + 2622464);  // 256x256 bf16
  unsigned short* catT  = (unsigned short*)(ws + 2753536);  // 512x512 bf16 [q][c]
  unsigned short* prob  = (unsigned short*)(ws + 3277824);  // 512x512 bf16 [q][k]
  unsigned short* h2T   = (unsigned short*)(ws + 3802112);  // 512x512 bf16 [q][o]

  hipLaunchKernelGGL(kinit, dim3(1), dim3(64), 0, stream,
                     (const unsigned*)mask, wsMin, wsFlag);
  hipLaunchKernelGGL(kconvert, dim3(704), dim3(256), 0, stream,
                     aW1, source, mW1, mW2, Cb, srcbf, mW1b, mW2b, aW1A, aW1B);
  hipLaunchKernelGGL(ktransp, dim3(32), dim3(256), 0, stream, x, catT, 512);
  hipLaunchKernelGGL(ktransp, dim3(32), dim3(256), 0, stream, source, srcT, 256);
  // U'[q][e] = xT @ aW1A + ab1
  hipLaunchKernelGGL((gemm_k<4, 8>),  dim3(32), dim3(256), 0, stream,
                     catT, 512, aW1A, 256, ab1, (void*)Up, 256, 4);
  // V[e][k] = aW1B @ source
  hipLaunchKernelGGL((gemm_k<0, 8>),  dim3(32), dim3(256), 0, stream,
                     aW1B, 256, srcT, 256, (const float*)nullptr, (void*)Vm, 512, 8);
  hipLaunchKernelGGL(kscores, dim3(4096), dim3(256), 0, stream,
                     dist, Cb, Up, Vm, aW2, ab2, scores, wsMin);
  hipLaunchKernelGGL(ksoftmax, dim3(512), dim3(256), 0, stream,
                     mask, wsMin, wsFlag, scores, prob);
  // msgT[q][d] = prob @ source^T  -> catT[:, 256:]
  hipLaunchKernelGGL((gemm_k<1, 16>), dim3(32), dim3(256), 0, stream,
                     prob, 512, srcbf, 512, (const float*)nullptr, (void*)(catT + 256), 512, 4);
  // h2T[q][o] = relu(catT @ mW1^T + mb1)
  hipLaunchKernelGGL((gemm_k<7, 16>), dim3(64), dim3(256), 0, stream,
                     catT, 512, mW1b, 512, mb1, (void*)h2T, 512, 8);
  // out[o2][q] = mW2 @ h2 + mb2
  hipLaunchKernelGGL((gemm_k<8, 16>), dim3(32), dim3(256), 0, stream,
                     mW2b, 512, h2T, 512, mb2, (void*)outMain, 512, 8);
}

// Round 4
// 177.844 us; speedup vs baseline: 1.3143x; 1.3143x over previous
//
#include <hip/hip_runtime.h>
#include <stdint.h>

#define D_ 256
#define NQ_ 512
#define NK_ 512
#define NP_ (NQ_*NK_)

typedef __attribute__((ext_vector_type(8))) __bf16 bf16x8;
typedef __attribute__((ext_vector_type(4))) float f32x4;

__device__ __forceinline__ unsigned short f2bf(float f) {
  unsigned u = __builtin_bit_cast(unsigned, f);
  u += 0x7FFFu + ((u >> 16) & 1u);   // RNE
  return (unsigned short)(u >> 16);
}
__device__ __forceinline__ unsigned encf(float f) {  // order-preserving float->uint
  unsigned u = __builtin_bit_cast(unsigned, f);
  return (u & 0x80000000u) ? ~u : (u | 0x80000000u);
}
__device__ __forceinline__ float decf(unsigned e) {
  unsigned u = (e & 0x80000000u) ? (e ^ 0x80000000u) : ~e;
  return __builtin_bit_cast(float, u);
}

// ---------------- shared GEMM body (direct-from-global MFMA) ----------------
// D[m][n] = sum_k A[m][k]*B[n][k] (+bias) ; A [M][lda], B [N][ldb] bf16 row-major-in-k
// EPI bits: 1=bf16-out, 2=relu, 4=bias[col], 8=bias[row]
template<int EPI, int KTILES>
__device__ __forceinline__ void gemm_body(
    const unsigned short* __restrict__ A, int lda,
    const unsigned short* __restrict__ B, int ldb,
    const float* __restrict__ bias,
    void* __restrict__ Dst, int ldd, int nTilesN, int bid) {
  const int t = threadIdx.x, w = t >> 6, l = t & 63, l15 = l & 15, g = l >> 4;
  const int bm = bid / nTilesN, bn = bid % nTilesN;
  const int m0 = bm*64 + w*16, n0 = bn*64;
  const unsigned short* Ap = A + (size_t)(m0 + l15)*lda + g*8;
  const unsigned short* Bp = B + (size_t)(n0 + l15)*ldb + g*8;
  f32x4 acc[4];
  #pragma unroll
  for (int n = 0; n < 4; ++n) acc[n] = (f32x4){0.f,0.f,0.f,0.f};
  #pragma unroll 2
  for (int kk = 0; kk < KTILES; ++kk) {
    bf16x8 a = *(const bf16x8*)(Ap + kk*32);
    #pragma unroll
    for (int n = 0; n < 4; ++n) {
      bf16x8 b = *(const bf16x8*)(Bp + (size_t)n*16*ldb + kk*32);
      acc[n] = __builtin_amdgcn_mfma_f32_16x16x32_bf16(a, b, acc[n], 0, 0, 0);
    }
  }
  #pragma unroll
  for (int n = 0; n < 4; ++n) {
    const int col = n0 + n*16 + l15;
    const float bc = (EPI & 4) ? bias[col] : 0.f;
    #pragma unroll
    for (int r = 0; r < 4; ++r) {
      const int m = m0 + g*4 + r;
      float v = acc[n][r] + bc;
      if (EPI & 8) v += bias[m];
      if (EPI & 2) v = fmaxf(v, 0.f);
      if (EPI & 1) ((unsigned short*)Dst)[(size_t)m*ldd + col] = f2bf(v);
      else         ((float*)Dst)[(size_t)m*ldd + col] = v;
    }
  }
}

template<int EPI, int KTILES>
__global__ __launch_bounds__(256) void gemm_k(
    const unsigned short* __restrict__ A, int lda,
    const unsigned short* __restrict__ B, int ldb,
    const float* __restrict__ bias,
    void* __restrict__ Dst, int ldd, int nTilesN) {
  gemm_body<EPI, KTILES>(A, lda, B, ldb, bias, Dst, ldd, nTilesN, blockIdx.x);
}

// ---------------- kprep: kinit + conversions + transposes, fused ----------------
// blocks: 0 = init; [1,705) convert regions; [705,737) x->catT; [737,769) source->srcT
__global__ __launch_bounds__(256) void kprep(
    const unsigned* __restrict__ maskw, unsigned* __restrict__ wsMin,
    unsigned* __restrict__ wsFlag,
    const float* __restrict__ aW1, const float* __restrict__ source,
    const float* __restrict__ x, const float* __restrict__ mW1,
    const float* __restrict__ mW2,
    unsigned short* __restrict__ Cb, unsigned short* __restrict__ srcbf,
    unsigned short* __restrict__ mW1b, unsigned short* __restrict__ mW2b,
    unsigned short* __restrict__ aW1A, unsigned short* __restrict__ aW1B,
    unsigned short* __restrict__ catT, unsigned short* __restrict__ srcT) {
  __shared__ float tile[64][65];
  const int b = blockIdx.x, t = threadIdx.x;
  if (b == 0) {
    if (t < 64) {
      unsigned a01 = 1, af = 1;
      for (int i = 0; i < 4; ++i) {
        unsigned v = maskw[t*4 + i];
        a01 &= (v == 0u || v == 1u) ? 1u : 0u;
        af  &= (v == 0u || v == 0x3f800000u) ? 1u : 0u;
      }
      unsigned long long b01 = __ballot(a01 != 0), bf = __ballot(af != 0);
      if (t == 0) {
        *wsFlag = (b01 == ~0ull) ? 1u : ((bf == ~0ull) ? 2u : 0u);
        *wsMin = 0xFFFFFFFFu;
      }
    }
    return;
  }
  if (b < 705) {
    const int bb = b - 1;
    const float* src; unsigned short* dst;
    if (bb < 64)        { int j = bb*1024 + t*4;       int e=j>>8, c=j&255; src = aW1 + e*768 + 512 + c; dst = Cb + j; }
    else if (bb < 192)  { int j = (bb-64)*1024 + t*4;  src = source + j;    dst = srcbf + j; }
    else if (bb < 448)  { int j = (bb-192)*1024 + t*4; src = mW1 + j;       dst = mW1b + j; }
    else if (bb < 576)  { int j = (bb-448)*1024 + t*4; src = mW2 + j;       dst = mW2b + j; }
    else if (bb < 640)  { int j = (bb-576)*1024 + t*4; int e=j>>8, c=j&255; src = aW1 + e*768 + c;       dst = aW1A + j; }
    else                { int j = (bb-640)*1024 + t*4; int e=j>>8, c=j&255; src = aW1 + e*768 + 256 + c; dst = aW1B + j; }
    const float4 v = *(const float4*)src;
    ushort4 o; o.x=f2bf(v.x); o.y=f2bf(v.y); o.z=f2bf(v.z); o.w=f2bf(v.w);
    *(ushort4*)dst = o;
    return;
  }
  // tiled transpose f32 [256][512] -> bf16 [512][ldd]
  const float* src; unsigned short* dst; int ldd, bid;
  if (b < 737) { src = x;      dst = catT; ldd = 512; bid = b - 705; }
  else         { src = source; dst = srcT; ldd = 256; bid = b - 737; }
  const int bd = bid >> 3, bq = bid & 7;
  const int r = t >> 4, c4 = (t & 15) * 4;
  #pragma unroll
  for (int rr = 0; rr < 4; ++rr) {
    int dl = rr*16 + r;
    float4 v = *(const float4*)(src + (size_t)(bd*64 + dl)*512 + bq*64 + c4);
    tile[dl][c4+0] = v.x; tile[dl][c4+1] = v.y; tile[dl][c4+2] = v.z; tile[dl][c4+3] = v.w;
  }
  __syncthreads();
  #pragma unroll
  for (int rr = 0; rr < 4; ++rr) {
    int j = rr*16 + r;
    ushort4 o;
    o.x = f2bf(tile[c4+0][j]); o.y = f2bf(tile[c4+1][j]);
    o.z = f2bf(tile[c4+2][j]); o.w = f2bf(tile[c4+3][j]);
    *(ushort4*)(dst + (size_t)(bq*64 + j)*ldd + bd*64 + c4) = o;
  }
}

// ---------------- kprep2: Up and Vm GEMMs in one launch ----------------
__global__ __launch_bounds__(256) void kprep2(
    const unsigned short* __restrict__ catT, const unsigned short* __restrict__ aW1A,
    const float* __restrict__ ab1, float* __restrict__ Up,
    const unsigned short* __restrict__ aW1B, const unsigned short* __restrict__ srcT,
    float* __restrict__ Vm) {
  if (blockIdx.x < 32)
    gemm_body<4, 8>(catT, 512, aW1A, 256, ab1, (void*)Up, 256, 4, blockIdx.x);
  else
    gemm_body<0, 8>(aW1B, 256, srcT, 256, (const float*)nullptr, (void*)Vm, 512, 8, blockIdx.x - 32);
}

// ---------------- KB: fused scores GEMM, 2-barrier block-cooperative staging ----------------
// block = 64 pairs, M=256 (4 waves), K=256. All dist loads issued up front;
// K staged to LDS in two halves (8-deep chunk-XOR swizzle); A direct from L2 Cb.
__global__ __launch_bounds__(256) void kscores(
    const float* __restrict__ dist, const unsigned short* __restrict__ Cb,
    const float* __restrict__ Up, const float* __restrict__ Vm,
    const float* __restrict__ aW2, const float* __restrict__ ab2,
    float* __restrict__ outScores, unsigned* __restrict__ wsMin) {
  __shared__ __align__(16) unsigned char ldsB[2][64*256]; // [half][pair row=256B swizzled]
  __shared__ float u_s[256], aw2_s[256];
  __shared__ float red[4][64];

  const int t = threadIdx.x;
  const int w = t >> 6;
  const int l = t & 63;
  const int l15 = l & 15;
  const int g = l >> 4;

  const int p0 = blockIdx.x * 64;
  const int q  = p0 >> 9;
  const int k0 = p0 & 511;

  const int quad1 = (w + g) & 3;
  const int quad2 = quad1 + 4;

  // ---- issue all 64 dist loads (wave-coalesced 64B segments per 16-lane group)
  float st[64];
  const float* dbase = dist + (size_t)p0 + l;
  #pragma unroll
  for (int kk = 0; kk < 8; ++kk) {
    #pragma unroll
    for (int i = 0; i < 4; ++i) {
      st[kk*8 + i]     = dbase[(size_t)(kk*32 + quad1*4 + i) * NP_];
      st[kk*8 + 4 + i] = dbase[(size_t)(kk*32 + quad2*4 + i) * NP_];
    }
  }

  u_s[t]   = Up[q*256 + t];
  aw2_s[t] = aW2[t];

  f32x4 acc[4][4];
  #pragma unroll
  for (int m = 0; m < 4; ++m)
    #pragma unroll
    for (int n = 0; n < 4; ++n) acc[m][n] = (f32x4){0.f, 0.f, 0.f, 0.f};

  const unsigned short* Abase = Cb + (size_t)(w*64 + l15)*256 + g*8;

  #pragma unroll
  for (int h = 0; h < 2; ++h) {
    // ---- convert + write this half's 32 staged values to LDS[h]
    #pragma unroll
    for (int kk2 = 0; kk2 < 4; ++kk2) {
      const int kk = h*4 + kk2;
      {
        const int c0 = kk2*32 + quad1*4;   // ch within half
        unsigned lo = (unsigned)f2bf(st[kk*8+0]) | ((unsigned)f2bf(st[kk*8+1]) << 16);
        unsigned hi = (unsigned)f2bf(st[kk*8+2]) | ((unsigned)f2bf(st[kk*8+3]) << 16);
        *(uint2*)(&ldsB[h][l*256 + (((c0>>3) ^ (l&7)) << 4) + ((c0>>2)&1)*8]) = make_uint2(lo, hi);
      }
      {
        const int c0 = kk2*32 + quad2*4;
        unsigned lo = (unsigned)f2bf(st[kk*8+4]) | ((unsigned)f2bf(st[kk*8+5]) << 16);
        unsigned hi = (unsigned)f2bf(st[kk*8+6]) | ((unsigned)f2bf(st[kk*8+7]) << 16);
        *(uint2*)(&ldsB[h][l*256 + (((c0>>3) ^ (l&7)) << 4) + ((c0>>2)&1)*8]) = make_uint2(lo, hi);
      }
    }
    __syncthreads();
    // ---- compute 4 K-steps from LDS[h]
    #pragma unroll
    for (int kk2 = 0; kk2 < 4; ++kk2) {
      const int kk = h*4 + kk2;
      bf16x8 a[4], bfrag[4];
      #pragma unroll
      for (int m = 0; m < 4; ++m)
        a[m] = *(const bf16x8*)(Abase + (size_t)m*16*256 + kk*32);
      #pragma unroll
      for (int n = 0; n < 4; ++n) {
        const int j = n*16 + l15;
        const int c0 = kk2*32 + g*8;
        bfrag[n] = *(const bf16x8*)(&ldsB[h][j*256 + (((c0>>3) ^ (j&7)) << 4)]);
      }
      #pragma unroll
      for (int m = 0; m < 4; ++m)
        #pragma unroll
        for (int n = 0; n < 4; ++n)
          acc[m][n] = __builtin_amdgcn_mfma_f32_16x16x32_bf16(a[m], bfrag[n], acc[m][n], 0, 0, 0);
    }
  }

  // ---- epilogue: score[j] = ab2 + sum_e aW2[e]*relu(T + U' + V)
  float part[4];
  #pragma unroll
  for (int n = 0; n < 4; ++n) {
    int j = k0 + n*16 + l15;
    float s = 0.f;
    #pragma unroll
    for (int m = 0; m < 4; ++m) {
      #pragma unroll
      for (int r = 0; r < 4; ++r) {
        int e = w*64 + m*16 + g*4 + r;
        float gv = acc[m][n][r] + u_s[e] + Vm[e*512 + j];
        s += aw2_s[e] * fmaxf(gv, 0.f);
      }
    }
    s += __shfl_xor(s, 16);
    s += __shfl_xor(s, 32);
    part[n] = s;
  }
  if (l < 16) {
    #pragma unroll
    for (int n = 0; n < 4; ++n) red[w][n*16 + l] = part[n];
  }
  __syncthreads();
  if (t < 64) {
    float s = red[0][t] + red[1][t] + red[2][t] + red[3][t] + ab2[0];
    outScores[p0 + t] = s;
    float mn = s;
    #pragma unroll
    for (int off = 32; off; off >>= 1) mn = fminf(mn, __shfl_xor(mn, off));
    if (t == 0) atomicMin(wsMin, encf(mn));
  }
}

// ---------------- KS: mask + softmax -> masked scores (out) + prob bf16 ----------------
__global__ __launch_bounds__(256) void ksoftmax(
    const void* __restrict__ maskp,
    const unsigned* __restrict__ wsMin, const unsigned* __restrict__ wsFlag,
    float* __restrict__ scores, unsigned short* __restrict__ prob) {
  __shared__ float srow[512];
  __shared__ float redl[8];
  const int t = threadIdx.x, w = t >> 6, l = t & 63;
  const int q = blockIdx.x;
  const float neg = decf(*wsMin) - 20.0f;
  const unsigned flag = *wsFlag;

  for (int k = t; k < 512; k += 256) {
    float raw = scores[q*512 + k];
    bool mv;
    if (flag == 1)      mv = ((const int*)maskp)[q*512 + k] != 0;
    else if (flag == 2) mv = ((const float*)maskp)[q*512 + k] != 0.f;
    else                mv = ((const unsigned char*)maskp)[q*512 + k] != 0;
    float ms = raw + (mv ? 0.f : neg);
    scores[q*512 + k] = ms;
    srow[k] = ms;
  }
  __syncthreads();
  float lm = fmaxf(srow[t], srow[t + 256]);
  #pragma unroll
  for (int off = 32; off; off >>= 1) lm = fmaxf(lm, __shfl_xor(lm, off));
  if (l == 0) redl[w] = lm;
  __syncthreads();
  float rmax = fmaxf(fmaxf(redl[0], redl[1]), fmaxf(redl[2], redl[3]));
  float e0 = __expf(srow[t] - rmax), e1 = __expf(srow[t + 256] - rmax);
  float ls = e0 + e1;
  #pragma unroll
  for (int off = 32; off; off >>= 1) ls += __shfl_xor(ls, off);
  if (l == 0) redl[4 + w] = ls;
  __syncthreads();
  float inv = 1.0f / (redl[4] + redl[5] + redl[6] + redl[7]);
  prob[q*512 + t]       = f2bf(e0 * inv);
  prob[q*512 + t + 256] = f2bf(e1 * inv);
}

extern "C" void kernel_launch(void* const* d_in, const int* in_sizes, int n_in,
                              void* d_out, int out_size, void* d_ws, size_t ws_size,
                              hipStream_t stream) {
  const float* x      = (const float*)d_in[0];
  const float* source = (const float*)d_in[1];
  const float* dist   = (const float*)d_in[2];
  const void*  mask   = (const void*)d_in[3];
  const float* aW1    = (const float*)d_in[4];
  const float* ab1    = (const float*)d_in[5];
  const float* aW2    = (const float*)d_in[6];
  const float* ab2    = (const float*)d_in[7];
  const float* mW1    = (const float*)d_in[8];
  const float* mb1    = (const float*)d_in[9];
  const float* mW2    = (const float*)d_in[10];
  const float* mb2    = (const float*)d_in[11];

  float* outMain = (float*)d_out;             // (1,256,512)
  float* scores  = outMain + 256*512;         // (1,512,512)

  char* ws = (char*)d_ws;
  unsigned* wsMin  = (unsigned*)ws;
  unsigned* wsFlag = wsMin + 1;
  unsigned short* Cb    = (unsigned short*)(ws + 1024);     // 256x256 bf16
  float*          Up    = (float*)(ws + 132096);            // 512x256 f32
  float*          Vm    = (float*)(ws + 656384);            // 256x512 f32
  unsigned short* srcbf = (unsigned short*)(ws + 1180672);  // 256x512 bf16 [d][k]
  unsigned short* srcT  = (unsigned short*)(ws + 1442816);  // 512x256 bf16 [k][c]
  unsigned short* mW1b  = (unsigned short*)(ws + 1704960);  // 512x512 bf16
  unsigned short* mW2b  = (unsigned short*)(ws + 2229248);  // 256x512 bf16
  unsigned short* aW1A  = (unsigned short*)(ws + 2491392);  // 256x256 bf16
  unsigned short* aW1B  = (unsigned short*)(ws + 2622464);  // 256x256 bf16
  unsigned short* catT  = (unsigned short*)(ws + 2753536);  // 512x512 bf16 [q][c]
  unsigned short* prob  = (unsigned short*)(ws + 3277824);  // 512x512 bf16 [q][k]
  unsigned short* h2T   = (unsigned short*)(ws + 3802112);  // 512x512 bf16 [q][o]

  hipLaunchKernelGGL(kprep, dim3(769), dim3(256), 0, stream,
                     (const unsigned*)mask, wsMin, wsFlag, aW1, source, x, mW1, mW2,
                     Cb, srcbf, mW1b, mW2b, aW1A, aW1B, catT, srcT);
  hipLaunchKernelGGL(kprep2, dim3(64), dim3(256), 0, stream,
                     catT, aW1A, ab1, Up, aW1B, srcT, Vm);
  hipLaunchKernelGGL(kscores, dim3(4096), dim3(256), 0, stream,
                     dist, Cb, Up, Vm, aW2, ab2, scores, wsMin);
  hipLaunchKernelGGL(ksoftmax, dim3(512), dim3(256), 0, stream,
                     mask, wsMin, wsFlag, scores, prob);
  // msgT[q][d] = prob @ source^T  -> catT[:, 256:]
  hipLaunchKernelGGL((gemm_k<1, 16>), dim3(32), dim3(256), 0, stream,
                     prob, 512, srcbf, 512, (const float*)nullptr, (void*)(catT + 256), 512, 4);
  // h2T[q][o] = relu(catT @ mW1^T + mb1)
  hipLaunchKernelGGL((gemm_k<7, 16>), dim3(64), dim3(256), 0, stream,
                     catT, 512, mW1b, 512, mb1, (void*)h2T, 512, 8);
  // out[o2][q] = mW2 @ h2 + mb2
  hipLaunchKernelGGL((gemm_k<8, 16>), dim3(32), dim3(256), 0, stream,
                     mW2b, 512, h2T, 512, mb2, (void*)outMain, 512, 8);
}